// Round 5
// baseline (225.547 us; speedup 1.0000x reference)
//
#include <hip/hip_runtime.h>

// Ragged gather-to-padded for SparseConvUnet preprocessing.
// feature: [Nrows, 128] f32 packed; atom_num: [N] int32 in [0,14);
// out = concat( padded [N,14,128] f32 (zero where slot>=atom_num), label as f32 [N] ).
//
// R5: identical to R4 except stores are PLAIN (write-back via L2) instead of
// nontemporal; loads stay nontemporal. A/B on the store cache hint.

#define MAX_ATOMS 14
#define CCH 128
#define F4_PER_ROW 32                       // 128 floats = 32 float4
#define F4_PER_RES (MAX_ATOMS * F4_PER_ROW) // 448 = 7 * 64
#define RPB 16                              // residues per gather block (4 waves * 4)
#define RES_PER_WAVE 4

typedef float f32x4 __attribute__((ext_vector_type(4)));

// ---- kernel 1: per-256-residue chunk sums ----
__global__ __launch_bounds__(256) void k_sums(const int* __restrict__ atom_num,
                                              int n, int* __restrict__ sums) {
    __shared__ int lds[256];
    int t = threadIdx.x;
    int r = blockIdx.x * 256 + t;
    lds[t] = (r < n) ? atom_num[r] : 0;
    __syncthreads();
    for (int d = 128; d > 0; d >>= 1) {
        if (t < d) lds[t] += lds[t + d];
        __syncthreads();
    }
    if (t == 0) sums[blockIdx.x] = lds[0];
}

// ---- kernel 2: gather ----
__global__ __launch_bounds__(256) void k_gather(
        const f32x4* __restrict__ feat,
        const int* __restrict__ atom_num,
        const int* __restrict__ sums,      // [nb] chunk totals
        const int* __restrict__ label,
        f32x4* __restrict__ out,
        float* __restrict__ out_label,
        int n) {
    __shared__ int red[256];
    __shared__ int off_s[RPB];
    __shared__ int cnt_s[RPB];
    int t = threadIdx.x;
    int rbase = blockIdx.x * RPB;
    int c      = rbase >> 8;               // scan chunk index
    int j0     = rbase & 255;              // residue offset within chunk
    int chunk0 = c << 8;

    // base = sum_{j<c} sums[j] + sum_{i<j0} atom_num[chunk0+i]   (all L2-hot)
    int part = 0;
    for (int j = t; j < c; j += 256) part += sums[j];        // <=2 steps
    if (t < j0) part += atom_num[chunk0 + t];                // j0<=240, 1 step
    red[t] = part;
    __syncthreads();
    for (int d = 128; d > 0; d >>= 1) {
        if (t < d) red[t] += red[t + d];
        __syncthreads();
    }
    int base = red[0];

    if (t < RPB) {
        int r = rbase + t;
        cnt_s[t] = (r < n) ? atom_num[r] : 0;
        if (r < n) out_label[r] = (float)label[r];  // harness reads d_out as f32
    }
    __syncthreads();
    if (t < RPB) {
        int o = base;
        #pragma unroll
        for (int i = 0; i < RPB; ++i) o += (i < t) ? cnt_s[i] : 0;
        off_s[t] = o;
    }
    __syncthreads();

    int wv   = t >> 6;                     // wave id 0..3
    int lane = t & 63;
    int halfrow = lane >> 5;               // 0 or 1: which row of the pair

    for (int j = 0; j < RES_PER_WAVE; ++j) {
        int rl = wv * RES_PER_WAVE + j;    // residue within block
        int r  = rbase + rl;
        if (r >= n) break;
        int off = off_s[rl];               // wave-uniform (one LDS read/residue)
        int cnt = cnt_s[rl];
        const f32x4* fp = feat + (size_t)off * F4_PER_ROW + lane;
        f32x4* op = out + (size_t)r * F4_PER_RES + lane;
        #pragma unroll
        for (int i = 0; i < 7; ++i) {
            f32x4 v = (f32x4)0.f;
            if (2 * i + halfrow < cnt)
                v = __builtin_nontemporal_load(fp + i * 64);
            op[i * 64] = v;                // plain store (write-back L2)
        }
    }
}

extern "C" void kernel_launch(void* const* d_in, const int* in_sizes, int n_in,
                              void* d_out, int out_size, void* d_ws, size_t ws_size,
                              hipStream_t stream) {
    const float* feature = (const float*)d_in[0];
    const int* atom_num  = (const int*)d_in[1];
    const int* label     = (const int*)d_in[2];
    const int n = in_sizes[1];               // N_res = 100000

    float* out = (float*)d_out;
    float* out_label = out + (size_t)n * MAX_ATOMS * CCH;

    int* ws_sums = (int*)d_ws;               // nb ints

    int nb = (n + 255) / 256;                // 391 for n=100000
    k_sums<<<nb, 256, 0, stream>>>(atom_num, n, ws_sums);

    int gb = (n + RPB - 1) / RPB;            // 6250 blocks
    k_gather<<<gb, 256, 0, stream>>>((const f32x4*)feature, atom_num,
                                     ws_sums, label,
                                     (f32x4*)out, out_label, n);
}

// Round 6
// 206.916 us; speedup vs baseline: 1.0900x; 1.0900x over previous
//
#include <hip/hip_runtime.h>

// Ragged gather-to-padded for SparseConvUnet preprocessing.
// feature: [Nrows, 128] f32 packed; atom_num: [N] int32 in [0,14);
// out = concat( padded [N,14,128] f32 (zero where slot>=atom_num), label as f32 [N] ).
//
// R6: stream-concurrency experiment. Gather = 512 blocks x 1024 threads
// (exactly 2 blocks/CU resident), grid-stride over 16-residue tiles ->
// 512 sequential write streams (16/HBM channel), ~58 MB moving front,
// zero LDS/sync in the streaming kernel. Offsets precomputed by k_prep.

#define MAX_ATOMS 14
#define F4_PER_ROW 32                       // 128 floats = 32 float4
#define F4_PER_RES (MAX_ATOMS * F4_PER_ROW) // 448 = 7 * 64
#define TILE 16                             // residues per block-iteration (= waves/block)
#define GBLOCKS 512
#define GTHREADS 1024

typedef float f32x4 __attribute__((ext_vector_type(4)));

// ---- kernel A: per-256-residue chunk sums ----
__global__ __launch_bounds__(256) void k_sums(const int* __restrict__ atom_num,
                                              int n, int* __restrict__ sums) {
    __shared__ int lds[256];
    int t = threadIdx.x;
    int r = blockIdx.x * 256 + t;
    lds[t] = (r < n) ? atom_num[r] : 0;
    __syncthreads();
    for (int d = 128; d > 0; d >>= 1) {
        if (t < d) lds[t] += lds[t + d];
        __syncthreads();
    }
    if (t == 0) sums[blockIdx.x] = lds[0];
}

// ---- kernel B: per-residue offsets + label cast ----
__global__ __launch_bounds__(256) void k_prep(const int* __restrict__ atom_num,
                                              const int* __restrict__ sums,
                                              const int* __restrict__ label,
                                              int n,
                                              int* __restrict__ offsets,
                                              float* __restrict__ out_label) {
    __shared__ int red[256];
    __shared__ int scn[256];
    int t = threadIdx.x;
    int b = blockIdx.x;
    // base = sum sums[0..b)  (L2-hot, <=2 strided loads + tree reduce)
    int part = 0;
    for (int j = t; j < b; j += 256) part += sums[j];
    red[t] = part;
    __syncthreads();
    for (int d = 128; d > 0; d >>= 1) {
        if (t < d) red[t] += red[t + d];
        __syncthreads();
    }
    int base = red[0];
    // exclusive scan of this chunk's atom_num
    int r = b * 256 + t;
    int v = (r < n) ? atom_num[r] : 0;
    scn[t] = v;
    __syncthreads();
    for (int d = 1; d < 256; d <<= 1) {
        int add = (t >= d) ? scn[t - d] : 0;
        __syncthreads();
        scn[t] += add;
        __syncthreads();
    }
    if (r < n) {
        offsets[r] = base + scn[t] - v;
        out_label[r] = (float)label[r];     // harness reads d_out as f32
    }
}

// ---- kernel C: pure streaming gather, fully resident, lockstep front ----
__global__ __launch_bounds__(GTHREADS, 8) void k_gather(
        const f32x4* __restrict__ feat,
        const int* __restrict__ atom_num,
        const int* __restrict__ offsets,
        f32x4* __restrict__ out,
        int n, int ntiles) {
    int w       = threadIdx.x >> 6;        // wave 0..15
    int lane    = threadIdx.x & 63;
    int halfrow = lane >> 5;               // which row of the lane's pair

    for (int tile = blockIdx.x; tile < ntiles; tile += GBLOCKS) {
        int r = tile * TILE + w;           // one residue per wave
        if (r < n) {
            int off = offsets[r];          // wave-uniform broadcast load (L2-hot)
            int cnt = atom_num[r];
            const f32x4* fp = feat + (size_t)off * F4_PER_ROW + lane;
            f32x4* op = out + (size_t)r * F4_PER_RES + lane;
            #pragma unroll
            for (int i = 0; i < 7; ++i) {
                f32x4 v = (f32x4)0.f;
                if (2 * i + halfrow < cnt)
                    v = __builtin_nontemporal_load(fp + i * 64);
                __builtin_nontemporal_store(v, op + i * 64);
            }
        }
    }
}

extern "C" void kernel_launch(void* const* d_in, const int* in_sizes, int n_in,
                              void* d_out, int out_size, void* d_ws, size_t ws_size,
                              hipStream_t stream) {
    const float* feature = (const float*)d_in[0];
    const int* atom_num  = (const int*)d_in[1];
    const int* label     = (const int*)d_in[2];
    const int n = in_sizes[1];               // N_res = 100000

    float* out = (float*)d_out;
    float* out_label = out + (size_t)n * MAX_ATOMS * 128;

    int nb = (n + 255) / 256;                // 391
    int* ws_sums    = (int*)d_ws;            // nb ints
    int* ws_offsets = ws_sums + nb;          // n ints

    k_sums<<<nb, 256, 0, stream>>>(atom_num, n, ws_sums);
    k_prep<<<nb, 256, 0, stream>>>(atom_num, ws_sums, label, n,
                                   ws_offsets, out_label);

    int ntiles = (n + TILE - 1) / TILE;      // 6250
    k_gather<<<GBLOCKS, GTHREADS, 0, stream>>>(
        (const f32x4*)feature, atom_num, ws_offsets,
        (f32x4*)out, n, ntiles);
}